// Round 6
// baseline (120.939 us; speedup 1.0000x reference)
//
#include <hip/hip_runtime.h>
#include <hip/hip_bf16.h>

#define BSZ 4
#define NN 2048
#define HH 768
#define NOUT 2304            // 3*HH (Q,K,V fused along N)
#define NHEAD 12
#define HD 64
#define DEG 16
#define NREL 64
#define MTOT (BSZ * NN)      // 8192
#define ETOT (MTOT * DEG)    // 131072

typedef __attribute__((ext_vector_type(4))) float f32x4;
typedef __attribute__((ext_vector_type(8))) short bf16x8;

__device__ __forceinline__ unsigned short f2bf(float f) {
    union { float f; unsigned int u; } v; v.f = f;
    unsigned int r = v.u + 0x7FFFu + ((v.u >> 16) & 1u);   // RNE
    return (unsigned short)(r >> 16);
}
__device__ __forceinline__ float bf2f(unsigned short u) {
    union { unsigned int u; float f; } v; v.u = ((unsigned int)u) << 16;
    return v.f;
}

__device__ __forceinline__ void gload16(const unsigned short* g, unsigned short* l) {
    __builtin_amdgcn_global_load_lds(
        (const __attribute__((address_space(1))) unsigned int*)g,
        (__attribute__((address_space(3))) unsigned int*)l,
        16, 0, 0);
}

// ---------------------------------------------------------------------------
// X (8192x768 f32) -> bf16.
// ---------------------------------------------------------------------------
__global__ __launch_bounds__(256) void convert_x(
    const float* __restrict__ X, unsigned short* __restrict__ Xb)
{
    const size_t i = ((size_t)blockIdx.x * 256 + threadIdx.x) * 8;
    const float4 a = *(const float4*)(X + i);
    const float4 b = *(const float4*)(X + i + 4);
    bf16x8 o;
    o[0] = f2bf(a.x); o[1] = f2bf(a.y); o[2] = f2bf(a.z); o[3] = f2bf(a.w);
    o[4] = f2bf(b.x); o[5] = f2bf(b.y); o[6] = f2bf(b.z); o[7] = f2bf(b.w);
    *(bf16x8*)(Xb + i) = o;
}

// ---------------------------------------------------------------------------
// Wq/Wk/Wv -> Wcat bf16 rows [0,2304); biases -> biasb[0,2304).
// ---------------------------------------------------------------------------
__global__ __launch_bounds__(256) void convert_w(
    const float* __restrict__ Wq, const float* __restrict__ Wk,
    const float* __restrict__ Wv,
    const float* __restrict__ bq, const float* __restrict__ bk,
    const float* __restrict__ bv,
    unsigned short* __restrict__ Wb, float* __restrict__ biasb)
{
    const int tid = blockIdx.x * 256 + threadIdx.x;
    const size_t i = (size_t)tid * 8;
    const int row = (int)(i / HH);
    const size_t off = i - (size_t)row * HH;
    const float* src = (row < HH) ? (Wq + (size_t)row * HH)
                     : (row < 2 * HH) ? (Wk + (size_t)(row - HH) * HH)
                                      : (Wv + (size_t)(row - 2 * HH) * HH);
    const float4 a = *(const float4*)(src + off);
    const float4 b = *(const float4*)(src + off + 4);
    bf16x8 o;
    o[0] = f2bf(a.x); o[1] = f2bf(a.y); o[2] = f2bf(a.z); o[3] = f2bf(a.w);
    o[4] = f2bf(b.x); o[5] = f2bf(b.y); o[6] = f2bf(b.z); o[7] = f2bf(b.w);
    *(bf16x8*)(Wb + i) = o;

    if (tid < NOUT) {
        biasb[tid] = (tid < HH) ? bq[tid]
                   : (tid < 2 * HH) ? bk[tid - HH] : bv[tid - 2 * HH];
    }
}

// ---------------------------------------------------------------------------
// Ek, Ev (each 64x768 f32) -> bf16. 48 blocks (24 each).
// ---------------------------------------------------------------------------
__global__ __launch_bounds__(256) void convert_e(
    const float* __restrict__ Ek, const float* __restrict__ Ev,
    unsigned short* __restrict__ Ekb, unsigned short* __restrict__ Evb)
{
    const int blk = (int)blockIdx.x;
    const int h2  = blk / 24;                        // 0: Ek, 1: Ev
    const int b2  = blk % 24;
    const float* src = h2 ? Ev : Ek;
    unsigned short* dst = h2 ? Evb : Ekb;
    const size_t i = ((size_t)b2 * 256 + threadIdx.x) * 8;
    const float4 a = *(const float4*)(src + i);
    const float4 b = *(const float4*)(src + i + 4);
    bf16x8 o;
    o[0] = f2bf(a.x); o[1] = f2bf(a.y); o[2] = f2bf(a.z); o[3] = f2bf(a.w);
    o[4] = f2bf(b.x); o[5] = f2bf(b.y); o[6] = f2bf(b.z); o[7] = f2bf(b.w);
    *(bf16x8*)(dst + i) = o;
}

// ---------------------------------------------------------------------------
// Fused QKV GEMM v6: C[m,n] = Xb[m,:].Wb[n,:] + biasb[n], m<8192, n<2304.
// 256x128 tile, BK=32, 512 threads (8 waves, 4x2), explicit double-buffer
// (T3 minimum 2-phase: stage t+1 issued before compute of t, one barrier
// per tile), XOR slot-swizzle on LDS (8-way -> 2-way bank conflicts; both
// sides: pre-swizzled global source + swizzled read slot, per-lane consts).
// Operand-swapped MFMA -> packed ushort4 stores. Bijective XCD swizzle.
// ---------------------------------------------------------------------------
__global__ __launch_bounds__(512) void qkv_mfma(
    const unsigned short* __restrict__ Xb,
    const unsigned short* __restrict__ Wb,
    const float* __restrict__ biasb,
    unsigned short* __restrict__ Qb,
    unsigned short* __restrict__ Kb, unsigned short* __restrict__ Vb)
{
    __shared__ unsigned short As0[256 * 32], As1[256 * 32];   // 16 KB each
    __shared__ unsigned short Bs0[128 * 32], Bs1[128 * 32];   //  8 KB each

    const int t    = threadIdx.x;
    const int lane = t & 63;
    const int w    = t >> 6;          // 0..7
    const int wr   = w >> 1;          // 0..3 (M)
    const int wc   = w & 1;           // 0..1 (N)

    // XCD swizzle: 576 wg = 8 x 72
    const int bid = blockIdx.y * 18 + blockIdx.x;
    const int swz = (bid & 7) * 72 + (bid >> 3);
    const int bn  = (swz % 18) * 128;
    const int bm  = (swz / 18) * 256;

    // staging: chunk c = w*64 + lane (16B each); row = c>>2, phys slot = c&3.
    // source reads LOGICAL slot = phys ^ (row&3) = (lane&3)^((lane>>2)&3).
    const int srow  = w * 16 + (lane >> 2);                       // 0..127
    const int sslot = ((lane & 3) ^ ((lane >> 2) & 3)) * 8;       // elems

    const unsigned short* Asrc0 = Xb + (size_t)(bm + srow) * HH + sslot;
    const unsigned short* Asrc1 = Xb + (size_t)(bm + 128 + srow) * HH + sslot;
    const unsigned short* Bsrc  = Wb + (size_t)(bn + srow) * HH + sslot;

    const int dstoff0 = w * 64 * 8;            // wave-uniform LDS elem offset
    const int dstoff1 = (512 + w * 64) * 8;

    f32x4 acc[4][4];     // [ni][mi], operand-swapped
    #pragma unroll
    for (int ni = 0; ni < 4; ++ni)
        #pragma unroll
        for (int mi = 0; mi < 4; ++mi)
            acc[ni][mi] = (f32x4){0.f, 0.f, 0.f, 0.f};

    const int fr  = lane & 15;
    // frag read: logical slot = lane>>4; row&3 = lane&3 -> phys slot:
    const int fkp = (((lane >> 4) ^ (lane & 3))) * 8;             // elems

#define STAGE(AS, BS, K0) do {                 \
    gload16(Asrc0 + (K0), (AS) + dstoff0);     \
    gload16(Asrc1 + (K0), (AS) + dstoff1);     \
    gload16(Bsrc  + (K0), (BS) + dstoff0);     \
} while (0)

#define COMPUTE(AS, BS) do {                                                  \
    bf16x8 a_[4], b_[4];                                                      \
    _Pragma("unroll")                                                         \
    for (int mi = 0; mi < 4; ++mi)                                            \
        a_[mi] = *(const bf16x8*)((AS) + (wr * 64 + mi * 16 + fr) * 32 + fkp);\
    _Pragma("unroll")                                                         \
    for (int ni = 0; ni < 4; ++ni)                                            \
        b_[ni] = *(const bf16x8*)((BS) + (wc * 64 + ni * 16 + fr) * 32 + fkp);\
    _Pragma("unroll")                                                         \
    for (int ni = 0; ni < 4; ++ni)                                            \
        _Pragma("unroll")                                                     \
        for (int mi = 0; mi < 4; ++mi)                                        \
            acc[ni][mi] = __builtin_amdgcn_mfma_f32_16x16x32_bf16(            \
                b_[ni], a_[mi], acc[ni][mi], 0, 0, 0);                        \
} while (0)

    STAGE(As0, Bs0, 0);
    __syncthreads();                          // drain vmcnt -> tile 0 ready
    for (int kt = 0; kt < 22; kt += 2) {
        STAGE(As1, Bs1, (kt + 1) * 32);       // issue BEFORE compute
        COMPUTE(As0, Bs0);                    // tile kt
        __syncthreads();                      // drain -> tile kt+1 ready
        STAGE(As0, Bs0, (kt + 2) * 32);
        COMPUTE(As1, Bs1);                    // tile kt+1
        __syncthreads();                      // drain -> tile kt+2 ready
    }
    STAGE(As1, Bs1, 23 * 32);
    COMPUTE(As0, Bs0);                        // tile 22
    __syncthreads();
    COMPUTE(As1, Bs1);                        // tile 23
#undef STAGE
#undef COMPUTE

    // epilogue: D reg-dim = N (4 consecutive cols), lane&15 = M
    const int cm = lane & 15;
    const int cn = (lane >> 4) * 4;

    unsigned short* outb; int ncol0;
    if (bn < HH)          { outb = Qb; ncol0 = bn; }
    else if (bn < 2 * HH) { outb = Kb; ncol0 = bn - HH; }
    else                  { outb = Vb; ncol0 = bn - 2 * HH; }

    #pragma unroll
    for (int ni = 0; ni < 4; ++ni) {
        const int nloc = wc * 64 + ni * 16 + cn;
        const float4 b4 = *(const float4*)(biasb + bn + nloc);
        #pragma unroll
        for (int mi = 0; mi < 4; ++mi) {
            const int grow = bm + wr * 64 + mi * 16 + cm;
            ushort4 o;
            o.x = f2bf(acc[ni][mi][0] + b4.x);
            o.y = f2bf(acc[ni][mi][1] + b4.y);
            o.z = f2bf(acc[ni][mi][2] + b4.z);
            o.w = f2bf(acc[ni][mi][3] + b4.w);
            *(ushort4*)(outb + (size_t)grow * HH + ncol0 + nloc) = o;
        }
    }
}

// ---------------------------------------------------------------------------
// S2[m, h*64+rel] = Qb[m, hslice] . Ekb[rel, hslice]   (K = 64, bf16 MFMA).
// ---------------------------------------------------------------------------
__global__ __launch_bounds__(256) void s2_kernel(
    const unsigned short* __restrict__ Qb,
    const unsigned short* __restrict__ Ekb,
    unsigned short* __restrict__ S2b)
{
    const int t    = threadIdx.x;
    const int lane = t & 63;
    const int w    = t >> 6;
    const int h    = blockIdx.y;
    const int m0   = blockIdx.x * 64 + w * 16;

    const int fr  = lane & 15;
    const int fk8 = (lane >> 4) * 8;

    bf16x8 a[2];
    #pragma unroll
    for (int kk = 0; kk < 2; ++kk)
        a[kk] = *(const bf16x8*)(Qb + (size_t)(m0 + fr) * HH + h * HD + kk * 32 + fk8);

    #pragma unroll
    for (int rt = 0; rt < 4; ++rt) {
        f32x4 acc = (f32x4){0.f, 0.f, 0.f, 0.f};
        #pragma unroll
        for (int kk = 0; kk < 2; ++kk) {
            const bf16x8 bfr = *(const bf16x8*)(
                Ekb + (size_t)(rt * 16 + fr) * HH + h * HD + kk * 32 + fk8);
            acc = __builtin_amdgcn_mfma_f32_16x16x32_bf16(bfr, a[kk], acc, 0, 0, 0);
        }
        const int m   = m0 + (lane & 15);
        const int rel = rt * 16 + (lane >> 4) * 4;
        ushort4 o;
        o.x = f2bf(acc[0]); o.y = f2bf(acc[1]);
        o.z = f2bf(acc[2]); o.w = f2bf(acc[3]);
        *(ushort4*)(S2b + (size_t)m * HH + h * HD + rel) = o;
    }
}

// ---------------------------------------------------------------------------
// Edge attention v5. 192 threads (3 waves x 4 heads), 1 block per segment.
// Q row + S2 row staged in LDS; all K loads hoisted; all 32 PV gather loads
// prefetched before the softmax chains (latency hides under phase A).
// Phase B: 192 threads = (head, 4-col) exactly, registers-only PV.
// ---------------------------------------------------------------------------
__global__ __launch_bounds__(192) void attn_kernel(
    const unsigned short* __restrict__ Qb, const unsigned short* __restrict__ Kb,
    const unsigned short* __restrict__ Vb,
    const unsigned short* __restrict__ S2b, const unsigned short* __restrict__ Evb,
    const int* __restrict__ eidx, float* __restrict__ out)
{
    const int seg  = blockIdx.x;          // b*N + dst
    const int t    = threadIdx.x;
    const int lane = t & 63;
    const int wave = t >> 6;              // 0..2

    __shared__ int s_src[DEG];
    __shared__ int s_rel[DEG];
    __shared__ unsigned short s_S2row[HH];
    __shared__ unsigned short s_Q[HH];
    __shared__ float s_attn[NHEAD][DEG];

    if (t < DEG) {
        s_src[t] = eidx[2 * ETOT + seg * DEG + t];
        s_rel[t] = eidx[3 * ETOT + seg * DEG + t];
    }
    if (t < 96)
        *(bf16x8*)(s_S2row + t * 8) = *(const bf16x8*)(S2b + (size_t)seg * HH + t * 8);
    else {
        const int tt = t - 96;
        *(bf16x8*)(s_Q + tt * 8) = *(const bf16x8*)(Qb + (size_t)seg * HH + tt * 8);
    }
    __syncthreads();

    const int b = seg >> 11;              // seg / N
    const int d = lane >> 2;              // edge group 0..15
    const int c = lane & 3;               // 16-col chunk 0..3

    // ---- hoisted K loads (4 heads x 2 halves per lane) ----
    const size_t krow = (size_t)(b * NN + s_src[d]) * HH;
    const int rel_d = s_rel[d];
    bf16x8 kf[4][2];
    #pragma unroll
    for (int hh = 0; hh < 4; ++hh) {
        const int col0 = (wave * 4 + hh) * HD + c * 16;
        kf[hh][0] = *(const bf16x8*)(Kb + krow + col0);
        kf[hh][1] = *(const bf16x8*)(Kb + krow + col0 + 8);
    }

    // ---- phase-B prefetch (issued now, consumed after phase A) ----
    const int hB   = t >> 4;              // 0..11
    const int cc   = t & 15;
    const int colB = hB * HD + cc * 4;
    ushort4 pv[DEG], pe[DEG];
    #pragma unroll
    for (int d2 = 0; d2 < DEG; ++d2) {
        pv[d2] = *(const ushort4*)(Vb + (size_t)(b * NN + s_src[d2]) * HH + colB);
        pe[d2] = *(const ushort4*)(Evb + (size_t)s_rel[d2] * HH + colB);
    }

    // ---- phase A: logits + softmax ----
    #pragma unroll
    for (int hh = 0; hh < 4; ++hh) {
        const int h    = wave * 4 + hh;
        const int col0 = h * HD + c * 16;
        const bf16x8 q0 = *(const bf16x8*)(s_Q + col0);
        const bf16x8 q1 = *(const bf16x8*)(s_Q + col0 + 8);

        float p = 0.f;
        #pragma unroll
        for (int i = 0; i < 8; ++i)
            p += bf2f((unsigned short)q0[i]) * bf2f((unsigned short)kf[hh][0][i]);
        #pragma unroll
        for (int i = 0; i < 8; ++i)
            p += bf2f((unsigned short)q1[i]) * bf2f((unsigned short)kf[hh][1][i]);

        p += __shfl_xor(p, 1, 64);
        p += __shfl_xor(p, 2, 64);
        const float logit = (p + bf2f(s_S2row[h * HD + rel_d])) * 0.125f;

        float mx = logit;
        #pragma unroll
        for (int m = 4; m < 64; m <<= 1) mx = fmaxf(mx, __shfl_xor(mx, m, 64));
        const float ex = __expf(logit - mx);
        float s = ex;
        #pragma unroll
        for (int m = 4; m < 64; m <<= 1) s += __shfl_xor(s, m, 64);
        if (c == 0) s_attn[h][d] = ex / s;
    }
    __syncthreads();

    // ---- phase B: weighted sum from prefetched registers ----
    f32x4 acc = (f32x4){0.f, 0.f, 0.f, 0.f};
    #pragma unroll
    for (int d2 = 0; d2 < DEG; ++d2) {
        const float aw = s_attn[hB][d2];
        acc[0] += aw * (bf2f(pv[d2].x) + bf2f(pe[d2].x));
        acc[1] += aw * (bf2f(pv[d2].y) + bf2f(pe[d2].y));
        acc[2] += aw * (bf2f(pv[d2].z) + bf2f(pe[d2].z));
        acc[3] += aw * (bf2f(pv[d2].w) + bf2f(pe[d2].w));
    }
    *(f32x4*)(out + (size_t)seg * HH + colB) = acc;
}

// ---------------------------------------------------------------------------
extern "C" void kernel_launch(void* const* d_in, const int* in_sizes, int n_in,
                              void* d_out, int out_size, void* d_ws, size_t ws_size,
                              hipStream_t stream)
{
    const float* X  = (const float*)d_in[0];
    const int* eidx = (const int*)d_in[1];
    const float* Wq = (const float*)d_in[2];
    const float* bq = (const float*)d_in[3];
    const float* Wk = (const float*)d_in[4];
    const float* bk = (const float*)d_in[5];
    const float* Wv = (const float*)d_in[6];
    const float* bv = (const float*)d_in[7];
    const float* Ek = (const float*)d_in[8];
    const float* Ev = (const float*)d_in[9];
    float* out = (float*)d_out;

    // workspace layout (16B-aligned slices), total ~66.7 MB
    char* ws = (char*)d_ws;
    unsigned short* Qb  = (unsigned short*)ws;                 // 12582912 B
    unsigned short* Kb  = (unsigned short*)(ws + 12582912);    // 12582912 B
    unsigned short* Vb  = (unsigned short*)(ws + 25165824);    // 12582912 B
    unsigned short* Xb  = (unsigned short*)(ws + 37748736);    // 12582912 B
    unsigned short* Wb  = (unsigned short*)(ws + 50331648);    //  3538944 B
    float* biasb        = (float*)(ws + 53870592);             //     9216 B
    unsigned short* S2b = (unsigned short*)(ws + 53879808);    // 12582912 B
    unsigned short* Ekb = (unsigned short*)(ws + 66462720);    //    98304 B
    unsigned short* Evb = (unsigned short*)(ws + 66561024);    //    98304 B

    convert_x<<<3072, 256, 0, stream>>>(X, Xb);
    convert_w<<<864, 256, 0, stream>>>(Wq, Wk, Wv, bq, bk, bv, Wb, biasb);
    convert_e<<<48, 256, 0, stream>>>(Ek, Ev, Ekb, Evb);

    dim3 g(NOUT / 128, MTOT / 256);      // 18 x 32 = 576
    qkv_mfma<<<g, 512, 0, stream>>>(Xb, Wb, biasb, Qb, Kb, Vb);

    s2_kernel<<<dim3(128, NHEAD), 256, 0, stream>>>(Qb, Ekb, S2b);

    attn_kernel<<<MTOT, 192, 0, stream>>>(Qb, Kb, Vb, S2b, Evb, eidx, out);
}

// Round 7
// 105.662 us; speedup vs baseline: 1.1446x; 1.1446x over previous
//
#include <hip/hip_runtime.h>
#include <hip/hip_bf16.h>

#define BSZ 4
#define NN 2048
#define HH 768
#define NOUT 2304            // 3*HH (Q,K,V fused along N)
#define NHEAD 12
#define HD 64
#define DEG 16
#define NREL 64
#define MTOT (BSZ * NN)      // 8192
#define ETOT (MTOT * DEG)    // 131072

typedef __attribute__((ext_vector_type(4))) float f32x4;
typedef __attribute__((ext_vector_type(8))) short bf16x8;

__device__ __forceinline__ unsigned short f2bf(float f) {
    union { float f; unsigned int u; } v; v.f = f;
    unsigned int r = v.u + 0x7FFFu + ((v.u >> 16) & 1u);   // RNE
    return (unsigned short)(r >> 16);
}
__device__ __forceinline__ float bf2f(unsigned short u) {
    union { unsigned int u; float f; } v; v.u = ((unsigned int)u) << 16;
    return v.f;
}

__device__ __forceinline__ void gload16(const unsigned short* g, unsigned short* l) {
    __builtin_amdgcn_global_load_lds(
        (const __attribute__((address_space(1))) unsigned int*)g,
        (__attribute__((address_space(3))) unsigned int*)l,
        16, 0, 0);
}

// ---------------------------------------------------------------------------
// X (8192x768 f32) -> bf16.
// ---------------------------------------------------------------------------
__global__ __launch_bounds__(256) void convert_x(
    const float* __restrict__ X, unsigned short* __restrict__ Xb)
{
    const size_t i = ((size_t)blockIdx.x * 256 + threadIdx.x) * 8;
    const float4 a = *(const float4*)(X + i);
    const float4 b = *(const float4*)(X + i + 4);
    bf16x8 o;
    o[0] = f2bf(a.x); o[1] = f2bf(a.y); o[2] = f2bf(a.z); o[3] = f2bf(a.w);
    o[4] = f2bf(b.x); o[5] = f2bf(b.y); o[6] = f2bf(b.z); o[7] = f2bf(b.w);
    *(bf16x8*)(Xb + i) = o;
}

// ---------------------------------------------------------------------------
// Wq/Wk/Wv -> Wcat bf16 rows [0,2304); biases -> biasb[0,2304).
// ---------------------------------------------------------------------------
__global__ __launch_bounds__(256) void convert_w(
    const float* __restrict__ Wq, const float* __restrict__ Wk,
    const float* __restrict__ Wv,
    const float* __restrict__ bq, const float* __restrict__ bk,
    const float* __restrict__ bv,
    unsigned short* __restrict__ Wb, float* __restrict__ biasb)
{
    const int tid = blockIdx.x * 256 + threadIdx.x;
    const size_t i = (size_t)tid * 8;
    const int row = (int)(i / HH);
    const size_t off = i - (size_t)row * HH;
    const float* src = (row < HH) ? (Wq + (size_t)row * HH)
                     : (row < 2 * HH) ? (Wk + (size_t)(row - HH) * HH)
                                      : (Wv + (size_t)(row - 2 * HH) * HH);
    const float4 a = *(const float4*)(src + off);
    const float4 b = *(const float4*)(src + off + 4);
    bf16x8 o;
    o[0] = f2bf(a.x); o[1] = f2bf(a.y); o[2] = f2bf(a.z); o[3] = f2bf(a.w);
    o[4] = f2bf(b.x); o[5] = f2bf(b.y); o[6] = f2bf(b.z); o[7] = f2bf(b.w);
    *(bf16x8*)(Wb + i) = o;

    if (tid < NOUT) {
        biasb[tid] = (tid < HH) ? bq[tid]
                   : (tid < 2 * HH) ? bk[tid - HH] : bv[tid - 2 * HH];
    }
}

// ---------------------------------------------------------------------------
// Ek, Ev (each 64x768 f32) -> bf16. 48 blocks (24 each).
// ---------------------------------------------------------------------------
__global__ __launch_bounds__(256) void convert_e(
    const float* __restrict__ Ek, const float* __restrict__ Ev,
    unsigned short* __restrict__ Ekb, unsigned short* __restrict__ Evb)
{
    const int blk = (int)blockIdx.x;
    const int h2  = blk / 24;                        // 0: Ek, 1: Ev
    const int b2  = blk % 24;
    const float* src = h2 ? Ev : Ek;
    unsigned short* dst = h2 ? Evb : Ekb;
    const size_t i = ((size_t)b2 * 256 + threadIdx.x) * 8;
    const float4 a = *(const float4*)(src + i);
    const float4 b = *(const float4*)(src + i + 4);
    bf16x8 o;
    o[0] = f2bf(a.x); o[1] = f2bf(a.y); o[2] = f2bf(a.z); o[3] = f2bf(a.w);
    o[4] = f2bf(b.x); o[5] = f2bf(b.y); o[6] = f2bf(b.z); o[7] = f2bf(b.w);
    *(bf16x8*)(dst + i) = o;
}

// ---------------------------------------------------------------------------
// Fused QKV GEMM v7: C[m,n] = Xb[m,:].Wb[n,:] + biasb[n], m<8192, n<2304.
// 256x128 tile, BK=32, 512 threads (8 waves, 4x2). T4 protocol: raw
// s_barrier + COUNTED vmcnt(3) -> next tile's 3 global_load_lds stay in
// flight across the barrier (no drain-to-0). Steady state per tile:
//   wait vmcnt(3); barrier; COMPUTE(buf); barrier; STAGE(buf, tile+2)
// Operand-swapped MFMA -> packed ushort4 stores. Bijective XCD swizzle.
// ---------------------------------------------------------------------------
__global__ __launch_bounds__(512) void qkv_mfma(
    const unsigned short* __restrict__ Xb,
    const unsigned short* __restrict__ Wb,
    const float* __restrict__ biasb,
    unsigned short* __restrict__ Qb,
    unsigned short* __restrict__ Kb, unsigned short* __restrict__ Vb)
{
    __shared__ unsigned short As0[256 * 32], As1[256 * 32];   // 16 KB each
    __shared__ unsigned short Bs0[128 * 32], Bs1[128 * 32];   //  8 KB each

    const int t    = threadIdx.x;
    const int lane = t & 63;
    const int w    = t >> 6;          // 0..7
    const int wr   = w >> 1;          // 0..3 (M)
    const int wc   = w & 1;           // 0..1 (N)

    // XCD swizzle: 576 wg = 8 x 72
    const int bid = blockIdx.y * 18 + blockIdx.x;
    const int swz = (bid & 7) * 72 + (bid >> 3);
    const int bn  = (swz % 18) * 128;
    const int bm  = (swz / 18) * 256;

    // staging: chunk = w*64 + lane (16B each); row = chunk>>2, slot = chunk&3
    // (XOR slot-swizzle kept from r6 — verified correct, bank-neutral)
    const int srow  = w * 16 + (lane >> 2);                       // 0..127
    const int sslot = ((lane & 3) ^ ((lane >> 2) & 3)) * 8;       // elems

    const unsigned short* Asrc0 = Xb + (size_t)(bm + srow) * HH + sslot;
    const unsigned short* Asrc1 = Xb + (size_t)(bm + 128 + srow) * HH + sslot;
    const unsigned short* Bsrc  = Wb + (size_t)(bn + srow) * HH + sslot;

    const int dstoff0 = w * 64 * 8;            // wave-uniform LDS elem offset
    const int dstoff1 = (512 + w * 64) * 8;

    f32x4 acc[4][4];     // [ni][mi], operand-swapped
    #pragma unroll
    for (int ni = 0; ni < 4; ++ni)
        #pragma unroll
        for (int mi = 0; mi < 4; ++mi)
            acc[ni][mi] = (f32x4){0.f, 0.f, 0.f, 0.f};

    const int fr  = lane & 15;
    const int fkp = (((lane >> 4) ^ (lane & 3))) * 8;             // elems

#define STAGE(AS, BS, K0) do {                 \
    gload16(Asrc0 + (K0), (AS) + dstoff0);     \
    gload16(Asrc1 + (K0), (AS) + dstoff1);     \
    gload16(Bsrc  + (K0), (BS) + dstoff0);     \
} while (0)

#define COMPUTE(AS, BS) do {                                                  \
    bf16x8 a_[4], b_[4];                                                      \
    _Pragma("unroll")                                                         \
    for (int mi = 0; mi < 4; ++mi)                                            \
        a_[mi] = *(const bf16x8*)((AS) + (wr * 64 + mi * 16 + fr) * 32 + fkp);\
    _Pragma("unroll")                                                         \
    for (int ni = 0; ni < 4; ++ni)                                            \
        b_[ni] = *(const bf16x8*)((BS) + (wc * 64 + ni * 16 + fr) * 32 + fkp);\
    _Pragma("unroll")                                                         \
    for (int ni = 0; ni < 4; ++ni)                                            \
        _Pragma("unroll")                                                     \
        for (int mi = 0; mi < 4; ++mi)                                        \
            acc[ni][mi] = __builtin_amdgcn_mfma_f32_16x16x32_bf16(            \
                b_[ni], a_[mi], acc[ni][mi], 0, 0, 0);                        \
} while (0)

#define WAITV3  asm volatile("s_waitcnt vmcnt(3)" ::: "memory")
#define WAITV0  asm volatile("s_waitcnt vmcnt(0)" ::: "memory")
#define BAR     do { __builtin_amdgcn_s_barrier();                  \
                     asm volatile("" ::: "memory"); } while (0)

    // prologue: prime both buffers (tiles 0 and 1); 6 loads in flight/wave
    STAGE(As0, Bs0, 0);
    STAGE(As1, Bs1, 32);

    // steady state: tiles 0..21 (11 double-steps); stage reaches tile 23
    for (int kt = 0; kt < 22; kt += 2) {
        WAITV3; BAR;                          // tile kt ready (own 3 + barrier)
        COMPUTE(As0, Bs0);
        BAR;                                  // all readers done with As0/Bs0
        STAGE(As0, Bs0, (kt + 2) * 32);
        WAITV3; BAR;                          // tile kt+1 ready
        COMPUTE(As1, Bs1);
        BAR;
        STAGE(As1, Bs1, (kt + 3) * 32);
    }
    WAITV3; BAR;                              // tile 22 ready
    COMPUTE(As0, Bs0);
    WAITV0; BAR;                              // tile 23 ready
    COMPUTE(As1, Bs1);
#undef STAGE
#undef COMPUTE
#undef WAITV3
#undef WAITV0
#undef BAR

    // epilogue: D reg-dim = N (4 consecutive cols), lane&15 = M
    const int cm = lane & 15;
    const int cn = (lane >> 4) * 4;

    unsigned short* outb; int ncol0;
    if (bn < HH)          { outb = Qb; ncol0 = bn; }
    else if (bn < 2 * HH) { outb = Kb; ncol0 = bn - HH; }
    else                  { outb = Vb; ncol0 = bn - 2 * HH; }

    #pragma unroll
    for (int ni = 0; ni < 4; ++ni) {
        const int nloc = wc * 64 + ni * 16 + cn;
        const float4 b4 = *(const float4*)(biasb + bn + nloc);
        #pragma unroll
        for (int mi = 0; mi < 4; ++mi) {
            const int grow = bm + wr * 64 + mi * 16 + cm;
            ushort4 o;
            o.x = f2bf(acc[ni][mi][0] + b4.x);
            o.y = f2bf(acc[ni][mi][1] + b4.y);
            o.z = f2bf(acc[ni][mi][2] + b4.z);
            o.w = f2bf(acc[ni][mi][3] + b4.w);
            *(ushort4*)(outb + (size_t)grow * HH + ncol0 + nloc) = o;
        }
    }
}

// ---------------------------------------------------------------------------
// Edge attention v6. 256 threads, 1 block per segment.
// Q·Ek folded into phase A (s2 kernel eliminated): lane (d,c) computes a
// 16-elem slice of BOTH Q·K[src] and Q·Ek[rel], sums them BEFORE the single
// shfl-reduce chain. Q staged in LDS; K/Ek loads hoisted across 3 heads.
// Phase B: t<192 = (head, 4-col), bf16 V + bf16 Ev weighted sum (r4 style).
// ---------------------------------------------------------------------------
__global__ __launch_bounds__(256) void attn_kernel(
    const unsigned short* __restrict__ Qb, const unsigned short* __restrict__ Kb,
    const unsigned short* __restrict__ Vb,
    const unsigned short* __restrict__ Ekb, const unsigned short* __restrict__ Evb,
    const int* __restrict__ eidx, float* __restrict__ out)
{
    const int seg  = blockIdx.x;          // b*N + dst
    const int t    = threadIdx.x;
    const int lane = t & 63;
    const int wave = t >> 6;              // 0..3

    __shared__ int s_src[DEG];
    __shared__ int s_rel[DEG];
    __shared__ unsigned short s_Q[HH];
    __shared__ float s_attn[NHEAD][DEG];

    if (t < DEG) {
        s_src[t] = eidx[2 * ETOT + seg * DEG + t];
        s_rel[t] = eidx[3 * ETOT + seg * DEG + t];
    }
    if (t >= 32 && t < 128) {
        const int tt = t - 32;
        *(bf16x8*)(s_Q + tt * 8) = *(const bf16x8*)(Qb + (size_t)seg * HH + tt * 8);
    }
    __syncthreads();

    const int b = seg >> 11;              // seg / N
    const int d = lane >> 2;              // edge group 0..15
    const int c = lane & 3;               // 16-col chunk 0..3

    const size_t krow = (size_t)(b * NN + s_src[d]) * HH;
    const size_t erow = (size_t)s_rel[d] * HH;

    // hoisted K + Ek loads (3 heads x 2 halves per lane)
    bf16x8 kf[3][2], ef[3][2];
    #pragma unroll
    for (int hh = 0; hh < 3; ++hh) {
        const int col0 = (wave * 3 + hh) * HD + c * 16;
        kf[hh][0] = *(const bf16x8*)(Kb + krow + col0);
        kf[hh][1] = *(const bf16x8*)(Kb + krow + col0 + 8);
        ef[hh][0] = *(const bf16x8*)(Ekb + erow + col0);
        ef[hh][1] = *(const bf16x8*)(Ekb + erow + col0 + 8);
    }

    #pragma unroll
    for (int hh = 0; hh < 3; ++hh) {
        const int h    = wave * 3 + hh;
        const int col0 = h * HD + c * 16;
        const bf16x8 q0 = *(const bf16x8*)(s_Q + col0);
        const bf16x8 q1 = *(const bf16x8*)(s_Q + col0 + 8);

        float p = 0.f;
        #pragma unroll
        for (int i = 0; i < 8; ++i) {
            const float qv0 = bf2f((unsigned short)q0[i]);
            const float qv1 = bf2f((unsigned short)q1[i]);
            p += qv0 * (bf2f((unsigned short)kf[hh][0][i]) + bf2f((unsigned short)ef[hh][0][i]));
            p += qv1 * (bf2f((unsigned short)kf[hh][1][i]) + bf2f((unsigned short)ef[hh][1][i]));
        }

        p += __shfl_xor(p, 1, 64);
        p += __shfl_xor(p, 2, 64);
        const float logit = p * 0.125f;

        float mx = logit;
        #pragma unroll
        for (int m = 4; m < 64; m <<= 1) mx = fmaxf(mx, __shfl_xor(mx, m, 64));
        const float ex = __expf(logit - mx);
        float s = ex;
        #pragma unroll
        for (int m = 4; m < 64; m <<= 1) s += __shfl_xor(s, m, 64);
        if (c == 0) s_attn[h][d] = ex / s;
    }
    __syncthreads();

    if (t < NHEAD * 16) {
        const int h    = t >> 4;
        const int cc   = t & 15;
        const int col0 = h * HD + cc * 4;
        f32x4 acc = (f32x4){0.f, 0.f, 0.f, 0.f};
        #pragma unroll
        for (int d2 = 0; d2 < DEG; ++d2) {
            const float aw = s_attn[h][d2];
            const ushort4 v4 = *(const ushort4*)(Vb + (size_t)(b * NN + s_src[d2]) * HH + col0);
            const ushort4 e4 = *(const ushort4*)(Evb + (size_t)s_rel[d2] * HH + col0);
            acc[0] += aw * (bf2f(v4.x) + bf2f(e4.x));
            acc[1] += aw * (bf2f(v4.y) + bf2f(e4.y));
            acc[2] += aw * (bf2f(v4.z) + bf2f(e4.z));
            acc[3] += aw * (bf2f(v4.w) + bf2f(e4.w));
        }
        *(f32x4*)(out + (size_t)seg * HH + col0) = acc;
    }
}

// ---------------------------------------------------------------------------
extern "C" void kernel_launch(void* const* d_in, const int* in_sizes, int n_in,
                              void* d_out, int out_size, void* d_ws, size_t ws_size,
                              hipStream_t stream)
{
    const float* X  = (const float*)d_in[0];
    const int* eidx = (const int*)d_in[1];
    const float* Wq = (const float*)d_in[2];
    const float* bq = (const float*)d_in[3];
    const float* Wk = (const float*)d_in[4];
    const float* bk = (const float*)d_in[5];
    const float* Wv = (const float*)d_in[6];
    const float* bv = (const float*)d_in[7];
    const float* Ek = (const float*)d_in[8];
    const float* Ev = (const float*)d_in[9];
    float* out = (float*)d_out;

    // workspace layout (16B-aligned slices), total ~54.1 MB
    char* ws = (char*)d_ws;
    unsigned short* Qb  = (unsigned short*)ws;                 // 12582912 B
    unsigned short* Kb  = (unsigned short*)(ws + 12582912);    // 12582912 B
    unsigned short* Vb  = (unsigned short*)(ws + 25165824);    // 12582912 B
    unsigned short* Xb  = (unsigned short*)(ws + 37748736);    // 12582912 B
    unsigned short* Wb  = (unsigned short*)(ws + 50331648);    //  3538944 B
    float* biasb        = (float*)(ws + 53870592);             //     9216 B
    unsigned short* Ekb = (unsigned short*)(ws + 53879808);    //    98304 B
    unsigned short* Evb = (unsigned short*)(ws + 53978112);    //    98304 B

    convert_x<<<3072, 256, 0, stream>>>(X, Xb);
    convert_w<<<864, 256, 0, stream>>>(Wq, Wk, Wv, bq, bk, bv, Wb, biasb);
    convert_e<<<48, 256, 0, stream>>>(Ek, Ev, Ekb, Evb);

    dim3 g(NOUT / 128, MTOT / 256);      // 18 x 32 = 576
    qkv_mfma<<<g, 512, 0, stream>>>(Xb, Wb, biasb, Qb, Kb, Vb);

    attn_kernel<<<MTOT, 256, 0, stream>>>(Qb, Kb, Vb, Ekb, Evb, eidx, out);
}